// Round 3
// baseline (305.356 us; speedup 1.0000x reference)
//
#include <hip/hip_runtime.h>

// FrequencyBandAverager: out[b,t,g,i,j] = mean over f in band g of x[b,t,f,i,j]
// x: (8,50,129,32,32) f32; freq_masks: (8,129) f32; out: (8,50,8,32,32) f32.
// Each input element belongs to exactly one band (bands are disjoint,
// contiguous f-ranges), so the optimal schedule reads x exactly once.

#define BT   400      // b*t = 8*50
#define NF   129      // rfft bins
#define NG   8        // bands
#define NC   1024     // 32*32 channels, contiguous innermost

__global__ __launch_bounds__(256)
void band_avg_kernel(const float* __restrict__ x,
                     const float* __restrict__ masks,
                     float* __restrict__ out)
{
    // grid: BT*NG blocks. block 256 threads, each thread handles one float4
    // (4 consecutive channels) -> 256*4 = 1024 = NC channels per block.
    const int blk = blockIdx.x;
    const int bt  = blk >> 3;   // / NG
    const int g   = blk & 7;    // % NG
    const int tid = threadIdx.x;

    // Derive this band's contiguous [start, end] f-range and bin count from
    // the mask row (robust to the exact FREQ_BINS values; assumes each band
    // is a contiguous run of 1.0s, true by construction).
    __shared__ int   s_start, s_end;
    __shared__ float s_cnt, s_inv;
    if (tid == 0) { s_start = NF; s_end = -1; s_cnt = 0.0f; }
    __syncthreads();
    if (tid < NF) {
        float m = masks[g * NF + tid];
        if (m > 0.0f) {
            atomicMin(&s_start, tid);
            atomicMax(&s_end, tid);
            atomicAdd(&s_cnt, m);
        }
    }
    __syncthreads();
    if (tid == 0) s_inv = 1.0f / s_cnt;
    __syncthreads();

    const int   f0  = s_start;
    const int   f1  = s_end;
    const float inv = s_inv;

    // x plane for (bt, f) is NC contiguous floats; thread tid owns float4 #tid.
    const float4* xin = reinterpret_cast<const float4*>(
                            x + (size_t)bt * NF * NC) + tid;
    float4 acc = make_float4(0.0f, 0.0f, 0.0f, 0.0f);
    for (int f = f0; f <= f1; ++f) {
        float4 v = xin[(size_t)f * (NC / 4)];
        acc.x += v.x; acc.y += v.y; acc.z += v.z; acc.w += v.w;
    }
    acc.x *= inv; acc.y *= inv; acc.z *= inv; acc.w *= inv;

    float4* o = reinterpret_cast<float4*>(
                    out + ((size_t)bt * NG + g) * NC) + tid;
    *o = acc;
}

extern "C" void kernel_launch(void* const* d_in, const int* in_sizes, int n_in,
                              void* d_out, int out_size, void* d_ws, size_t ws_size,
                              hipStream_t stream) {
    const float* x     = (const float*)d_in[0];
    const float* masks = (const float*)d_in[1];
    float*       out   = (float*)d_out;
    band_avg_kernel<<<dim3(BT * NG), dim3(256), 0, stream>>>(x, masks, out);
}

// Round 5
// 304.662 us; speedup vs baseline: 1.0023x; 1.0023x over previous
//
#include <hip/hip_runtime.h>

// FrequencyBandAverager: out[b,t,g,i,j] = mean over f in band g of x[b,t,f,i,j]
// x: (8,50,129,32,32) f32; freq_masks: (8,129) f32; out: (8,50,8,32,32) f32.
// Bands are disjoint contiguous f-ranges -> read x exactly once (211 MB) and
// write out once (13 MB); memory-bound floor ~36 us at 6.3 TB/s.
//
// Schedule notes:
//  - One 256-thread block per (bt, g); thread t owns float4 #t of the 1024-ch
//    plane -> 16 B/lane fully-coalesced loads, stride 4 KB over f.
//  - Band index g varies SLOWEST across blockIdx (g = blk/400). With g = blk%8
//    (previous round) band g landed entirely on XCD g (stride-8 round-robin),
//    a ~1.8x work imbalance since bands span 4..30 f-planes.
//  - Band [f0,f1] and count are derived by a block-uniform scalar scan of the
//    mask row (no LDS, no atomics, no barriers).

#define BT   400      // b*t = 8*50
#define NF   129      // rfft bins
#define NG   8        // bands
#define NC   1024     // 32*32 channels, contiguous innermost

typedef float v4f __attribute__((ext_vector_type(4)));

__global__ __launch_bounds__(256)
void band_avg_v2(const float* __restrict__ x,
                 const float* __restrict__ masks,
                 float* __restrict__ out)
{
    const int blk = blockIdx.x;
    const int bt  = blk % BT;   // fast-varying -> bt spreads across XCDs/CUs
    const int g   = blk / BT;   // each band's 400 blocks spread over all XCDs
    const int tid = threadIdx.x;

    // Block-uniform scan of this band's mask row; lives in SGPRs.
    int f0 = -1, f1 = -1;
    float cnt = 0.0f;
    for (int f = 0; f < NF; ++f) {
        float m = masks[g * NF + f];
        if (m > 0.0f) {
            if (f0 < 0) f0 = f;
            f1 = f;
            cnt += m;
        }
    }
    const float inv = 1.0f / cnt;

    const v4f* xin = reinterpret_cast<const v4f*>(x + (size_t)bt * NF * NC) + tid;

    v4f a0 = {0.0f, 0.0f, 0.0f, 0.0f};
    v4f a1 = {0.0f, 0.0f, 0.0f, 0.0f};
    int f = f0;
    for (; f + 1 <= f1; f += 2) {
        v4f u = xin[(size_t)f       * (NC / 4)];
        v4f w = xin[(size_t)(f + 1) * (NC / 4)];
        a0 += u;
        a1 += w;
    }
    if (f <= f1) {
        a0 += xin[(size_t)f * (NC / 4)];
    }
    v4f acc = (a0 + a1) * inv;

    v4f* o = reinterpret_cast<v4f*>(out + ((size_t)bt * NG + g) * NC) + tid;
    *o = acc;
}

extern "C" void kernel_launch(void* const* d_in, const int* in_sizes, int n_in,
                              void* d_out, int out_size, void* d_ws, size_t ws_size,
                              hipStream_t stream) {
    const float* x     = (const float*)d_in[0];
    const float* masks = (const float*)d_in[1];
    float*       out   = (float*)d_out;
    band_avg_v2<<<dim3(BT * NG), dim3(256), 0, stream>>>(x, masks, out);
}